// Round 1
// baseline (755.892 us; speedup 1.0000x reference)
//
#include <hip/hip_runtime.h>

// ---- problem constants ----
#define Bn 4
#define Nn 1024
#define Tn 12
#define Cn 256
#define Hn 8
#define DKn 32
#define Mrows 49152            // B*N*T
#define NEl 12582912LL         // B*N*T*C
#define SCALE_ 0.17677669529663687f  // 1/sqrt(32)

typedef __attribute__((ext_vector_type(4))) float f32x4;
typedef __attribute__((ext_vector_type(8))) short s16x8;

__device__ __forceinline__ ushort f2bfu(float x) {       // fp32 -> bf16 (RNE)
    unsigned u = __builtin_bit_cast(unsigned, x);
    u += 0x7fffu + ((u >> 16) & 1u);
    return (ushort)(u >> 16);
}
__device__ __forceinline__ float bfu2f(ushort h) {
    return __builtin_bit_cast(float, ((unsigned)h) << 16);
}

// ---------------- weight pre-conversion: fp32 -> bf16 hi + lo residual ----------------
struct WPtrs { const float* src[7]; };

__global__ __launch_bounds__(256)
void wconv_k(WPtrs w, ushort* __restrict__ Wh, ushort* __restrict__ Wl) {
    int idx = blockIdx.x * 256 + threadIdx.x;   // 7*65536 total, exact grid
    int which = idx >> 16, pos = idx & 65535;
    float x = w.src[which][pos];
    ushort h = f2bfu(x);
    Wh[idx] = h;
    Wl[idx] = f2bfu(x - bfu2f(h));
}

// ---------------- batched GEMM: Y[m,o] = sum_c A[m,c] * W[o,c] (+bias) ----------------
// BM=64, BN=256(full), BK=32; 256 threads = 4 waves; wave w owns cols [64w,64w+64).
// SPLIT: 3-pass bf16x3 (~fp32 accuracy) for the numerically sensitive projections.
struct GPtrs {
    const void*   A[4];
    const ushort* Wh[4];
    const ushort* Wl[4];
    void*         Y[4];
};

template<bool SPLIT, bool IN_BF16, bool OUT_BF16, bool BIAS>
__global__ __launch_bounds__(256)
void gemm_k(GPtrs p, const float* __restrict__ bias) {
    const int bt   = blockIdx.y;
    const int bm   = blockIdx.x * 64;
    const int tid  = threadIdx.x;
    const int lane = tid & 63;
    const int wave = tid >> 6;

    // stride 40 shorts (=80B) to spread LDS banks; keeps 16B alignment
    __shared__ short As[64 * 40];
    __shared__ short Bs[256 * 40];
    __shared__ short Al[SPLIT ? 64 * 40 : 8];
    __shared__ short Bl[SPLIT ? 256 * 40 : 8];

    f32x4 acc[4][4];
#pragma unroll
    for (int i = 0; i < 4; i++)
#pragma unroll
        for (int j = 0; j < 4; j++)
            acc[i][j] = (f32x4){0.f, 0.f, 0.f, 0.f};

    const int r  = tid >> 2;        // 0..63
    const int cq = (tid & 3) * 8;   // 0,8,16,24

    for (int k0 = 0; k0 < 256; k0 += 32) {
        // ---- stage A tile (64 x 32) ----
        if constexpr (IN_BF16) {
            const ushort* A = (const ushort*)p.A[bt];
            s16x8 v = *(const s16x8*)(A + (size_t)(bm + r) * 256 + k0 + cq);
            *(s16x8*)&As[r * 40 + cq] = v;
        } else {
            const float* A = (const float*)p.A[bt];
            const float* g = A + (size_t)(bm + r) * 256 + k0 + cq;
            f32x4 v0 = *(const f32x4*)g;
            f32x4 v1 = *(const f32x4*)(g + 4);
            s16x8 hi, lo;
#pragma unroll
            for (int j = 0; j < 8; j++) {
                float x = (j < 4) ? v0[j] : v1[j - 4];
                ushort hb = f2bfu(x);
                hi[j] = (short)hb;
                if constexpr (SPLIT) lo[j] = (short)f2bfu(x - bfu2f(hb));
            }
            *(s16x8*)&As[r * 40 + cq] = hi;
            if constexpr (SPLIT) *(s16x8*)&Al[r * 40 + cq] = lo;
        }
        // ---- stage W tile (256 x 32), already bf16 ----
#pragma unroll
        for (int pw = 0; pw < 4; pw++) {
            int orow = pw * 64 + r;
            *(s16x8*)&Bs[orow * 40 + cq] =
                *(const s16x8*)(p.Wh[bt] + (size_t)orow * 256 + k0 + cq);
            if constexpr (SPLIT)
                *(s16x8*)&Bl[orow * 40 + cq] =
                    *(const s16x8*)(p.Wl[bt] + (size_t)orow * 256 + k0 + cq);
        }
        __syncthreads();
        // ---- fragments + MFMA ----
        s16x8 a[4], al[4];
#pragma unroll
        for (int mi = 0; mi < 4; mi++) {
            int off = (mi * 16 + (lane & 15)) * 40 + (lane >> 4) * 8;
            a[mi] = *(const s16x8*)&As[off];
            if constexpr (SPLIT) al[mi] = *(const s16x8*)&Al[off];
        }
#pragma unroll
        for (int ni = 0; ni < 4; ni++) {
            int off = (wave * 64 + ni * 16 + (lane & 15)) * 40 + (lane >> 4) * 8;
            s16x8 b = *(const s16x8*)&Bs[off];
            s16x8 bl;
            if constexpr (SPLIT) bl = *(const s16x8*)&Bl[off];
#pragma unroll
            for (int mi = 0; mi < 4; mi++) {
                acc[mi][ni] = __builtin_amdgcn_mfma_f32_16x16x32_bf16(a[mi], b, acc[mi][ni], 0, 0, 0);
                if constexpr (SPLIT) {
                    acc[mi][ni] = __builtin_amdgcn_mfma_f32_16x16x32_bf16(al[mi], b,  acc[mi][ni], 0, 0, 0);
                    acc[mi][ni] = __builtin_amdgcn_mfma_f32_16x16x32_bf16(a[mi],  bl, acc[mi][ni], 0, 0, 0);
                }
            }
        }
        __syncthreads();
    }
    // ---- epilogue: C/D layout col=lane&15, row=(lane>>4)*4+reg ----
#pragma unroll
    for (int mi = 0; mi < 4; mi++) {
#pragma unroll
        for (int ni = 0; ni < 4; ni++) {
            int col  = wave * 64 + ni * 16 + (lane & 15);
            int row0 = bm + mi * 16 + (lane >> 4) * 4;
            float bv = BIAS ? bias[col] : 0.f;
#pragma unroll
            for (int rg = 0; rg < 4; rg++) {
                float v = acc[mi][ni][rg] + bv;
                size_t idx = (size_t)(row0 + rg) * 256 + col;
                if constexpr (OUT_BF16) ((ushort*)p.Y[bt])[idx] = f2bfu(v);
                else                    ((float*)p.Y[bt])[idx]  = v;
            }
        }
    }
}

// ---------------- attention: one wave per (b,n,h), all fp32 in LDS ----------------
__global__ __launch_bounds__(64)
void attn_k(const ushort* __restrict__ Qf, const float* __restrict__ Kf,
            const ushort* __restrict__ Vf, const float* __restrict__ Qs,
            const ushort* __restrict__ Ks, const ushort* __restrict__ Vs,
            const float* __restrict__ kj, const float* __restrict__ vf_fs,
            ushort* __restrict__ c0, ushort* __restrict__ c1,
            ushort* __restrict__ c2, ushort* __restrict__ c3)
{
    const int bn  = blockIdx.x;   // b*N + n
    const int h   = blockIdx.y;
    const int tid = threadIdx.x;

    __shared__ float sQf[12][33], sKf[12][33], sVf[12][33];
    __shared__ float sQs[12][33], sKs[12][33], sVs[12][33], sqf[12][33];
    __shared__ float S[4][12][13];

    const size_t base = (size_t)bn * (Tn * Cn) + (size_t)h * DKn;

    for (int i = tid; i < 384; i += 64) {
        int t = i >> 5, d = i & 31;
        size_t g = base + (size_t)t * Cn + d;
        sQf[t][d] = bfu2f(Qf[g]);
        sKf[t][d] = Kf[g];
        sVf[t][d] = bfu2f(Vf[g]);
        sQs[t][d] = Qs[g];
        sKs[t][d] = bfu2f(Ks[g]);
        sVs[t][d] = bfu2f(Vs[g]);
    }
    __syncthreads();
    // FlowSpeed physics transform (fp32, matches reference exactly)
    for (int i = tid; i < 384; i += 64) {
        int t = i >> 5, d = i & 31;
        float q = sQs[t][d];
        sqf[t][d] = kj[t] * (q - q * q / (vf_fs[t] + 1e-5f));
    }
    __syncthreads();
    // scores: 4 mats x 12 x 12, dot over d=32
    for (int i = tid; i < 576; i += 64) {
        int mat = i / 144, rem = i - mat * 144;
        int t = rem / 12, s = rem - t * 12;
        const float (*Am)[33], (*Bm)[33];
        if (mat == 0)      { Am = sQf; Bm = sKf; }   // z_ff
        else if (mat == 1) { Am = sKf; Bm = sqf; }   // z_fs
        else if (mat == 2) { Am = sKs; Bm = sQf; }   // z_sf
        else               { Am = sQs; Bm = sKs; }   // z_ss
        float acc = 0.f;
#pragma unroll
        for (int d = 0; d < 32; d++) acc += Am[t][d] * Bm[s][d];
        S[mat][t][s] = acc * SCALE_;
    }
    __syncthreads();
    // softmax over s (48 rows)
    if (tid < 48) {
        int mat = tid / 12, t = tid - mat * 12;
        float mx = -1e30f;
        for (int s = 0; s < 12; s++) mx = fmaxf(mx, S[mat][t][s]);
        float e[12], sum = 0.f;
        for (int s = 0; s < 12; s++) { e[s] = expf(S[mat][t][s] - mx); sum += e[s]; }
        float inv = 1.f / sum;
        for (int s = 0; s < 12; s++) S[mat][t][s] = e[s] * inv;
    }
    __syncthreads();
    // ctx: 4 mats x 12 x 32, dot over s=12; write bf16
    for (int i = tid; i < 1536; i += 64) {
        int mat = i / 384, rem = i - mat * 384;
        int t = rem >> 5, d = rem & 31;
        const float (*V)[33] = (mat < 2) ? sVf : sVs;
        float acc = 0.f;
#pragma unroll
        for (int s = 0; s < 12; s++) acc += S[mat][t][s] * V[s][d];
        ushort* dst = (mat == 0) ? c0 : (mat == 1) ? c1 : (mat == 2) ? c2 : c3;
        dst[base + (size_t)t * Cn + d] = f2bfu(acc);
    }
}

// ---------------- host launcher ----------------
extern "C" void kernel_launch(void* const* d_in, const int* in_sizes, int n_in,
                              void* d_out, int out_size, void* d_ws, size_t ws_size,
                              hipStream_t stream) {
    (void)in_sizes; (void)n_in; (void)out_size; (void)ws_size;

    const float* flow_q  = (const float*)d_in[0];
    const float* flow_k  = (const float*)d_in[1];
    const float* flow_v  = (const float*)d_in[2];
    const float* speed_q = (const float*)d_in[3];
    const float* speed_k = (const float*)d_in[4];
    const float* speed_v = (const float*)d_in[5];
    const float* w_fq  = (const float*)d_in[6];
    const float* w_fk  = (const float*)d_in[7];
    const float* w_fv  = (const float*)d_in[8];
    const float* w_sq  = (const float*)d_in[9];
    const float* w_sk  = (const float*)d_in[10];
    const float* w_sv  = (const float*)d_in[11];
    const float* w_out = (const float*)d_in[12];
    const float* b_out = (const float*)d_in[13];
    const float* kj    = (const float*)d_in[14];
    const float* vf    = (const float*)d_in[15];

    char* ws = (char*)d_ws;
    size_t off = 0;
    auto alloc = [&](size_t bytes) -> void* {
        void* p = ws + off;
        off += (bytes + 255) & ~(size_t)255;
        return p;
    };
    ushort* Wh = (ushort*)alloc(7 * 65536 * 2);   // bf16 hi for 7 weight mats
    ushort* Wl = (ushort*)alloc(7 * 65536 * 2);   // bf16 lo residual
    ushort* Qf = (ushort*)alloc(NEl * 2);
    float*  Kf = (float*) alloc(NEl * 4);         // fp32: sensitive (z_fs logits)
    ushort* Vf = (ushort*)alloc(NEl * 2);
    float*  Qs = (float*) alloc(NEl * 4);         // fp32: feeds physics transform
    ushort* Ks = (ushort*)alloc(NEl * 2);
    ushort* Vs = (ushort*)alloc(NEl * 2);
    ushort* c0 = (ushort*)alloc(NEl * 2);
    ushort* c1 = (ushort*)alloc(NEl * 2);
    ushort* c2 = (ushort*)alloc(NEl * 2);
    ushort* c3 = (ushort*)alloc(NEl * 2);

    float* out = (float*)d_out;

    // 0) convert weights once per launch
    WPtrs wp;
    wp.src[0] = w_fq; wp.src[1] = w_fk; wp.src[2] = w_fv; wp.src[3] = w_sq;
    wp.src[4] = w_sk; wp.src[5] = w_sv; wp.src[6] = w_out;
    wconv_k<<<dim3(7 * 65536 / 256), 256, 0, stream>>>(wp, Wh, Wl);

    // 1a) 4 insensitive projections: 1-pass bf16, bf16 out
    GPtrs p1;
    p1.A[0] = flow_q;  p1.Wh[0] = Wh + 0 * 65536; p1.Wl[0] = Wl + 0 * 65536; p1.Y[0] = Qf;
    p1.A[1] = flow_v;  p1.Wh[1] = Wh + 2 * 65536; p1.Wl[1] = Wl + 2 * 65536; p1.Y[1] = Vf;
    p1.A[2] = speed_k; p1.Wh[2] = Wh + 4 * 65536; p1.Wl[2] = Wl + 4 * 65536; p1.Y[2] = Ks;
    p1.A[3] = speed_v; p1.Wh[3] = Wh + 5 * 65536; p1.Wl[3] = Wl + 5 * 65536; p1.Y[3] = Vs;
    gemm_k<false, false, true, false><<<dim3(Mrows / 64, 4), 256, 0, stream>>>(p1, nullptr);

    // 1b) 2 sensitive projections: split bf16x3 (~fp32), fp32 out
    GPtrs p2;
    p2.A[0] = flow_k;  p2.Wh[0] = Wh + 1 * 65536; p2.Wl[0] = Wl + 1 * 65536; p2.Y[0] = Kf;
    p2.A[1] = speed_q; p2.Wh[1] = Wh + 3 * 65536; p2.Wl[1] = Wl + 3 * 65536; p2.Y[1] = Qs;
    p2.A[2] = flow_k;  p2.Wh[2] = Wh + 1 * 65536; p2.Wl[2] = Wl + 1 * 65536; p2.Y[2] = Kf; // unused
    p2.A[3] = flow_k;  p2.Wh[3] = Wh + 1 * 65536; p2.Wl[3] = Wl + 1 * 65536; p2.Y[3] = Kf; // unused
    gemm_k<true, false, false, false><<<dim3(Mrows / 64, 2), 256, 0, stream>>>(p2, nullptr);

    // 2) attention (fp32), writes bf16 ctx
    attn_k<<<dim3(Bn * Nn, Hn), 64, 0, stream>>>(Qf, Kf, Vf, Qs, Ks, Vs, kj, vf, c0, c1, c2, c3);

    // 3) out projections: bf16 in, fp32 out + bias
    GPtrs p3;
    p3.A[0] = c0; p3.Wh[0] = Wh + 6 * 65536; p3.Wl[0] = Wl + 6 * 65536; p3.Y[0] = out;
    p3.A[1] = c1; p3.Wh[1] = Wh + 6 * 65536; p3.Wl[1] = Wl + 6 * 65536; p3.Y[1] = out + NEl;
    p3.A[2] = c2; p3.Wh[2] = Wh + 6 * 65536; p3.Wl[2] = Wl + 6 * 65536; p3.Y[2] = out + 2 * NEl;
    p3.A[3] = c3; p3.Wh[3] = Wh + 6 * 65536; p3.Wl[3] = Wl + 6 * 65536; p3.Y[3] = out + 3 * NEl;
    gemm_k<false, true, false, true><<<dim3(Mrows / 64, 4), 256, 0, stream>>>(p3, b_out);
}